// Round 3
// baseline (355.461 us; speedup 1.0000x reference)
//
#include <hip/hip_runtime.h>

typedef unsigned short u16;
typedef __attribute__((ext_vector_type(8))) short bf16x8;   // 8 bf16 = 4 VGPR
typedef __attribute__((ext_vector_type(4))) float f32x4;

// Hardware round-to-nearest-even f32->bf16 (v_cvt_pk_bf16_f32 on gfx950).
// Same rounding as the previous manual bit-math; 1 op instead of 5.
__device__ __forceinline__ u16 f2b(float f){
  __bf16 h = (__bf16)f;
  return __builtin_bit_cast(u16, h);
}

// ---- K1: prep kernel. bx<2048: LayerNorm -> bf16 mnb [l][s][cm].
//           bx>=2048: weight pre-transpose to bf16 WT[z][n][cm]. ----
__global__ __launch_bounds__(256) void k_pre(const float* __restrict__ m,
    const float* __restrict__ lw, const float* __restrict__ lb,
    const float* __restrict__ wq, const float* __restrict__ wk,
    const float* __restrict__ wv, const float* __restrict__ wg,
    const float* __restrict__ wo,
    u16* __restrict__ mnb, u16* __restrict__ WT){
  __shared__ u16 T[16*264];
  int bx = blockIdx.x;
  int tid = threadIdx.x;
  if (bx < 2048){
    // LayerNorm: block = (l, 32-row s-band); one wave-row per iteration.
    int l = bx>>3;
    int s0 = (bx&7)*32 + (tid>>6)*8;   // 4 waves x 8 rows
    int ln = tid&63;
    float4 w = *(const float4*)(lw + ln*4);
    float4 b = *(const float4*)(lb + ln*4);
    #pragma unroll
    for (int i=0;i<8;++i){
      int s = s0 + i;
      float4 x = *(const float4*)(m + ((size_t)s*256 + l)*256 + ln*4);
      float s1 = x.x+x.y+x.z+x.w;
      float s2 = x.x*x.x + x.y*x.y + x.z*x.z + x.w*x.w;
      #pragma unroll
      for (int off=32; off>0; off>>=1){
        s1 += __shfl_xor(s1, off);
        s2 += __shfl_xor(s2, off);
      }
      float mu  = s1*(1.0f/256.0f);
      float inv = rsqrtf(s2*(1.0f/256.0f) - mu*mu + 1e-5f);
      u16 o[4];
      o[0] = f2b((x.x-mu)*inv*w.x + b.x);
      o[1] = f2b((x.y-mu)*inv*w.y + b.y);
      o[2] = f2b((x.z-mu)*inv*w.z + b.z);
      o[3] = f2b((x.w-mu)*inv*w.w + b.w);
      *(ushort4*)(mnb + ((size_t)l*256 + s)*256 + ln*4) = *(ushort4*)o;
    }
  } else {
    // Weight transpose: 80 blocks; z = 0..4 (wq,wk,wv,wg,wo), 16 n-cols each.
    int bb = bx - 2048;
    int z = bb>>4, n0 = (bb&15)*16;
    const float* W = (z==0)?wq:(z==1)?wk:(z==2)?wv:(z==3)?wg:wo;
    int nl = tid&15;
    #pragma unroll
    for (int i=0;i<16;++i){
      int cm = i*16 + (tid>>4);
      T[nl*264 + cm] = f2b(W[(size_t)cm*256 + n0 + nl]);   // 64B-coalesced reads
    }
    __syncthreads();
    int n = tid>>4, cc = (tid&15)*16;
    uint4 a = *(const uint4*)&T[n*264 + cc];
    uint4 c = *(const uint4*)&T[n*264 + cc + 8];
    *(uint4*)&WT[(size_t)z*65536 + (size_t)(n0+n)*256 + cc]     = a;
    *(uint4*)&WT[(size_t)z*65536 + (size_t)(n0+n)*256 + cc + 8] = c;
  }
}

// ---- K2: fully fused per (l,h): QKV proj -> attention -> gate -> out proj ----
// Out identity: block (l,h) -> out rows (s'=32h+(l>>3), l'=(l&7)*32+j), and
// O_flat[j][n] == o[s][c] at the same flat index (s*32+c == j*256+n).
__global__ __launch_bounds__(256,4) void k_fused(const u16* __restrict__ mnb,
    const u16* __restrict__ WT, const float* __restrict__ bg,
    const float* __restrict__ bo, float* __restrict__ outp){
  // LDS map (u16 units), total 19200 u16 = 38400 B -> 4 blocks/CU.
  //  SC  per-wave [16][40] scratch :     0 ..  2559  (q- and P-transpose)
  //  KS2 [cblk 4][t 256][8] k      :  2560 .. 10751  (b128 rows, clean banks)
  //  VT  [32][264] v^T[c][t]       : 10752 .. 19199
  //  OS  f32 [128][32] (phase 3)   : bytes 0..16383, aliases SC+KS2 (dead)
  //  GS  [32][264] gated bf16      : aliases VT (dead after phase 2)
  __shared__ u16 smem[19200];
  u16* KS2 = smem + 2560;
  u16* VT  = smem + 10752;
  float* OS = (float*)smem;
  u16* GS  = smem + 10752;

  int bx = blockIdx.x;
  // XCD-aware swizzle: XCD = bx%8; each XCD owns a contiguous 32-wide l-range,
  // 8 h-blocks per l adjacent in dispatch order.
  int l = ((bx&7)<<5) | (bx>>6);
  int h = (bx>>3)&7;
  int tid = threadIdx.x;
  int lane = tid&63, wid = tid>>6, quad = lane>>4, lo = lane&15;
  int m0 = wid*64;
  u16* SC = smem + wid*640;
  f32x4 z4 = {0.f,0.f,0.f,0.f};

  const u16* Abase = mnb + (size_t)l*65536;          // mn_l [s][cm]
  const u16* Bq = WT + (size_t)h*32*256;
  const u16* Bk = WT + (size_t)65536 + (size_t)h*32*256;
  const u16* Bv = WT + (size_t)2*65536 + (size_t)h*32*256;

  // ============ Phase 1a: q,k projection (split to cap registers) ============
  f32x4 aqk[4][4];                                   // [mt][0-1]=q, [2-3]=k
  #pragma unroll
  for (int a=0;a<4;++a)
    #pragma unroll
    for (int b=0;b<4;++b) aqk[a][b]=z4;
  for (int ks=0; ks<8; ++ks){
    bf16x8 af[4];
    #pragma unroll
    for (int mt=0; mt<4; ++mt)
      af[mt] = *(const bf16x8*)(Abase + (size_t)(m0+mt*16+lo)*256 + ks*32 + quad*8);
    bf16x8 bq2[2], bk2[2];
    #pragma unroll
    for (int c2=0; c2<2; ++c2){
      bq2[c2] = *(const bf16x8*)(Bq + (size_t)(c2*16+lo)*256 + ks*32 + quad*8);
      bk2[c2] = *(const bf16x8*)(Bk + (size_t)(c2*16+lo)*256 + ks*32 + quad*8);
    }
    #pragma unroll
    for (int mt=0; mt<4; ++mt)
      #pragma unroll
      for (int c2=0; c2<2; ++c2){
        aqk[mt][0+c2] = __builtin_amdgcn_mfma_f32_16x16x32_bf16(af[mt], bq2[c2], aqk[mt][0+c2], 0,0,0);
        aqk[mt][2+c2] = __builtin_amdgcn_mfma_f32_16x16x32_bf16(af[mt], bk2[c2], aqk[mt][2+c2], 0,0,0);
      }
  }
  // scatter k into KS2[cblk][t][8]
  #pragma unroll
  for (int mt=0; mt<4; ++mt)
    #pragma unroll
    for (int ntl=0; ntl<2; ++ntl)
      #pragma unroll
      for (int r=0; r<4; ++r){
        int t  = m0 + mt*16 + quad*4 + r;
        int cb = ntl*2 + (lo>>3);
        KS2[cb*2048 + t*8 + (lo&7)] = f2b(aqk[mt][2+ntl][r]);
      }
  // q transpose via per-wave scratch (wave-private, no barrier needed)
  bf16x8 qf[4];
  #pragma unroll
  for (int mt=0; mt<4; ++mt){
    #pragma unroll
    for (int ntl=0; ntl<2; ++ntl)
      #pragma unroll
      for (int r=0; r<4; ++r)
        SC[(quad*4+r)*40 + ntl*16+lo] = f2b(aqk[mt][0+ntl][r]);
    qf[mt] = *(const bf16x8*)&SC[lo*40 + quad*8];
  }

  // ============ Phase 1b: v projection ============
  f32x4 av[4][2];
  #pragma unroll
  for (int a=0;a<4;++a){ av[a][0]=z4; av[a][1]=z4; }
  for (int ks=0; ks<8; ++ks){
    bf16x8 af[4];
    #pragma unroll
    for (int mt=0; mt<4; ++mt)
      af[mt] = *(const bf16x8*)(Abase + (size_t)(m0+mt*16+lo)*256 + ks*32 + quad*8);
    bf16x8 bv2[2];
    #pragma unroll
    for (int c2=0; c2<2; ++c2)
      bv2[c2] = *(const bf16x8*)(Bv + (size_t)(c2*16+lo)*256 + ks*32 + quad*8);
    #pragma unroll
    for (int mt=0; mt<4; ++mt)
      #pragma unroll
      for (int c2=0; c2<2; ++c2)
        av[mt][c2] = __builtin_amdgcn_mfma_f32_16x16x32_bf16(af[mt], bv2[c2], av[mt][c2], 0,0,0);
  }
  #pragma unroll
  for (int mt=0; mt<4; ++mt)
    #pragma unroll
    for (int ntl=0; ntl<2; ++ntl)
      #pragma unroll
      for (int r=0; r<4; ++r){
        int t = m0 + mt*16 + quad*4 + r;
        VT[(ntl*16+lo)*264 + t] = f2b(av[mt][ntl][r]);
      }
  __syncthreads();   // B0: KS2/VT visible to all waves

  // ============ Phase 2: attention ============
  const float scale = 0.17677669529663687f;  // 1/sqrt(32)
  float lr[16];
  #pragma unroll
  for (int i=0;i<16;++i) lr[i]=0.f;
  f32x4 o_acc[4][2];
  #pragma unroll
  for (int a=0;a<4;++a){ o_acc[a][0]=z4; o_acc[a][1]=z4; }

  for (int ts=0; ts<8; ++ts){
    bf16x8 kf[2];
    #pragma unroll
    for (int ntl=0; ntl<2; ++ntl)
      kf[ntl] = *(const bf16x8*)&KS2[quad*2048 + (ts*32+ntl*16+lo)*8];
    bf16x8 vf[2];
    #pragma unroll
    for (int nc=0; nc<2; ++nc)
      vf[nc] = *(const bf16x8*)&VT[(nc*16+lo)*264 + ts*32 + quad*8];
    #pragma unroll
    for (int mt=0; mt<4; ++mt){
      f32x4 sa[2];
      sa[0] = __builtin_amdgcn_mfma_f32_16x16x32_bf16(qf[mt], kf[0], z4, 0,0,0);
      sa[1] = __builtin_amdgcn_mfma_f32_16x16x32_bf16(qf[mt], kf[1], z4, 0,0,0);
      #pragma unroll
      for (int ntl=0; ntl<2; ++ntl)
        #pragma unroll
        for (int r=0; r<4; ++r){
          float p = __expf(sa[ntl][r]*scale);
          lr[mt*4+r] += p;
          SC[(quad*4+r)*40 + ntl*16+lo] = f2b(p);
        }
      bf16x8 paf = *(const bf16x8*)&SC[lo*40 + quad*8];
      o_acc[mt][0] = __builtin_amdgcn_mfma_f32_16x16x32_bf16(paf, vf[0], o_acc[mt][0], 0,0,0);
      o_acc[mt][1] = __builtin_amdgcn_mfma_f32_16x16x32_bf16(paf, vf[1], o_acc[mt][1], 0,0,0);
    }
  }
  #pragma unroll
  for (int i=0;i<16;++i){
    float v = lr[i];
    v += __shfl_xor(v, 1);
    v += __shfl_xor(v, 2);
    v += __shfl_xor(v, 4);
    v += __shfl_xor(v, 8);
    lr[i] = 1.0f / v;
  }
  __syncthreads();   // B1: all waves done reading KS2/VT/SC

  // ============ Phase 3: gate GEMM [32 x 256], two j-halves ============
  int sp  = h*32 + (l>>3);      // s' (constant per block)
  int l0p = (l&7)*32;           // l' base; rows j = 0..31
  int wn0 = wid*64;             // this wave's 64-col slice of n
  const u16* Gw = WT + (size_t)3*65536;   // wg^T [n][cm]

  // waves 0,1 publish o rows s<128 (f32) into OS half-buffer
  if (wid < 2){
    #pragma unroll
    for (int mt=0; mt<4; ++mt)
      #pragma unroll
      for (int nc=0; nc<2; ++nc)
        #pragma unroll
        for (int r=0; r<4; ++r){
          int s = m0 + mt*16 + quad*4 + r;
          OS[s*32 + nc*16+lo] = o_acc[mt][nc][r] * lr[mt*4+r];
        }
  }
  // pass-0 ks-loop (global + mfma only; overlaps the OS writes)
  f32x4 gacc0[4];
  #pragma unroll
  for (int b=0;b<4;++b) gacc0[b]=z4;
  for (int ks=0; ks<8; ++ks){
    bf16x8 ga = *(const bf16x8*)(mnb + ((size_t)(l0p+lo)*256 + sp)*256 + ks*32 + quad*8);
    bf16x8 gb[4];
    #pragma unroll
    for (int nt=0; nt<4; ++nt)
      gb[nt] = *(const bf16x8*)(Gw + (size_t)(wn0+nt*16+lo)*256 + ks*32 + quad*8);
    #pragma unroll
    for (int nt=0; nt<4; ++nt)
      gacc0[nt] = __builtin_amdgcn_mfma_f32_16x16x32_bf16(ga, gb[nt], gacc0[nt], 0,0,0);
  }
  __syncthreads();   // B2: OS half-0 visible
  #pragma unroll
  for (int nt=0; nt<4; ++nt){
    int n = wn0 + nt*16 + lo;
    float bgn = bg[n];
    #pragma unroll
    for (int r=0; r<4; ++r){
      int j = quad*4 + r;                       // 0..15
      float g = 1.f/(1.f + __expf(-(gacc0[nt][r] + bgn)));
      int sidx = j*8 + (n>>5);                  // < 128
      GS[j*264 + n] = f2b(g * OS[sidx*32 + (n&31)]);
    }
  }
  __syncthreads();   // B3: pass-0 OS reads complete

  // waves 2,3 publish o rows s>=128
  if (wid >= 2){
    #pragma unroll
    for (int mt=0; mt<4; ++mt)
      #pragma unroll
      for (int nc=0; nc<2; ++nc)
        #pragma unroll
        for (int r=0; r<4; ++r){
          int s = m0 + mt*16 + quad*4 + r - 128;
          OS[s*32 + nc*16+lo] = o_acc[mt][nc][r] * lr[mt*4+r];
        }
  }
  f32x4 gacc1[4];
  #pragma unroll
  for (int b=0;b<4;++b) gacc1[b]=z4;
  for (int ks=0; ks<8; ++ks){
    bf16x8 ga = *(const bf16x8*)(mnb + ((size_t)(l0p+16+lo)*256 + sp)*256 + ks*32 + quad*8);
    bf16x8 gb[4];
    #pragma unroll
    for (int nt=0; nt<4; ++nt)
      gb[nt] = *(const bf16x8*)(Gw + (size_t)(wn0+nt*16+lo)*256 + ks*32 + quad*8);
    #pragma unroll
    for (int nt=0; nt<4; ++nt)
      gacc1[nt] = __builtin_amdgcn_mfma_f32_16x16x32_bf16(ga, gb[nt], gacc1[nt], 0,0,0);
  }
  __syncthreads();   // B4: OS half-1 visible
  #pragma unroll
  for (int nt=0; nt<4; ++nt){
    int n = wn0 + nt*16 + lo;
    float bgn = bg[n];
    #pragma unroll
    for (int r=0; r<4; ++r){
      int jj = quad*4 + r;
      int j = 16 + jj;                          // 16..31
      float g = 1.f/(1.f + __expf(-(gacc1[nt][r] + bgn)));
      int sidx = jj*8 + (n>>5);                 // row - 128
      GS[j*264 + n] = f2b(g * OS[sidx*32 + (n&31)]);
    }
  }
  __syncthreads();   // B5: GS fully written

  // ============ Phase 4: out projection [32 x 256] ============
  const u16* Ow = WT + (size_t)4*65536;   // wo^T
  f32x4 pacc[2][4];
  #pragma unroll
  for (int a=0;a<2;++a)
    #pragma unroll
    for (int b=0;b<4;++b) pacc[a][b]=z4;
  for (int ks=0; ks<8; ++ks){
    bf16x8 pa[2];
    #pragma unroll
    for (int mt2=0; mt2<2; ++mt2)
      pa[mt2] = *(const bf16x8*)&GS[(mt2*16+lo)*264 + ks*32 + quad*8];
    bf16x8 pb[4];
    #pragma unroll
    for (int nt=0; nt<4; ++nt)
      pb[nt] = *(const bf16x8*)(Ow + (size_t)(wn0+nt*16+lo)*256 + ks*32 + quad*8);
    #pragma unroll
    for (int mt2=0; mt2<2; ++mt2)
      #pragma unroll
      for (int nt=0; nt<4; ++nt)
        pacc[mt2][nt] = __builtin_amdgcn_mfma_f32_16x16x32_bf16(pa[mt2], pb[nt], pacc[mt2][nt], 0,0,0);
  }
  #pragma unroll
  for (int nt=0; nt<4; ++nt){
    int n = wn0 + nt*16 + lo;
    float bon = bo[n];
    #pragma unroll
    for (int mt2=0; mt2<2; ++mt2)
      #pragma unroll
      for (int r=0; r<4; ++r){
        int j = mt2*16 + quad*4 + r;
        outp[((size_t)sp*256 + l0p + j)*256 + n] = pacc[mt2][nt][r] + bon;
      }
  }
}

extern "C" void kernel_launch(void* const* d_in, const int* in_sizes, int n_in,
                              void* d_out, int out_size, void* d_ws, size_t ws_size,
                              hipStream_t stream){
  const float* m  = (const float*)d_in[0];
  const float* lw = (const float*)d_in[1];
  const float* lb = (const float*)d_in[2];
  const float* wq = (const float*)d_in[3];
  const float* wk = (const float*)d_in[4];
  const float* wv = (const float*)d_in[5];
  const float* wg = (const float*)d_in[6];
  const float* bg = (const float*)d_in[7];
  const float* wo = (const float*)d_in[8];
  const float* bo = (const float*)d_in[9];

  // ws: mnb bf16 [l][s][cm] = 32 MiB | WT bf16 [5][256][256] = 640 KiB
  u16* mnb = (u16*)d_ws;
  u16* WT  = mnb + (size_t)16777216;
  float* out = (float*)d_out;

  k_pre  <<<2128, 256, 0, stream>>>(m, lw, lb, wq, wk, wv, wg, wo, mnb, WT);
  k_fused<<<2048, 256, 0, stream>>>(mnb, WT, bg, bo, out);
}

// Round 4
// 308.533 us; speedup vs baseline: 1.1521x; 1.1521x over previous
//
#include <hip/hip_runtime.h>

typedef unsigned short u16;
typedef __attribute__((ext_vector_type(8))) short bf16x8;   // 8 bf16 = 4 VGPR
typedef __attribute__((ext_vector_type(4))) float f32x4;

// Hardware round-to-nearest-even f32->bf16 (single v_cvt instr on gfx950).
// Identical rounding to the manual bit-math used by the verified pipeline.
__device__ __forceinline__ u16 f2b(float f){
  __bf16 h = (__bf16)f;
  return __builtin_bit_cast(u16, h);
}

// ---- K1: prep kernel. bx<2048: LayerNorm -> bf16 mnb [l][s][cm] AND
//          mnb2 [s][l][cm].  bx>=2048: weight transpose to bf16 WT[z][n][cm].
__global__ __launch_bounds__(256) void k_pre(const float* __restrict__ m,
    const float* __restrict__ lw, const float* __restrict__ lb,
    const float* __restrict__ wq, const float* __restrict__ wk,
    const float* __restrict__ wv, const float* __restrict__ wg,
    const float* __restrict__ wo,
    u16* __restrict__ mnb, u16* __restrict__ mnb2, u16* __restrict__ WT){
  __shared__ u16 T[16*264];
  int bx = blockIdx.x;
  int tid = threadIdx.x;
  if (bx < 2048){
    // LayerNorm: block = (l, 32-row s-band); one wave-row per iteration.
    int l = bx>>3;
    int s0 = (bx&7)*32 + (tid>>6)*8;   // 4 waves x 8 rows
    int ln = tid&63;
    float4 w = *(const float4*)(lw + ln*4);
    float4 b = *(const float4*)(lb + ln*4);
    #pragma unroll
    for (int i=0;i<8;++i){
      int s = s0 + i;
      float4 x = *(const float4*)(m + ((size_t)s*256 + l)*256 + ln*4);
      float s1 = x.x+x.y+x.z+x.w;
      float s2 = x.x*x.x + x.y*x.y + x.z*x.z + x.w*x.w;
      #pragma unroll
      for (int off=32; off>0; off>>=1){
        s1 += __shfl_xor(s1, off);
        s2 += __shfl_xor(s2, off);
      }
      float mu  = s1*(1.0f/256.0f);
      float inv = rsqrtf(s2*(1.0f/256.0f) - mu*mu + 1e-5f);
      u16 o[4];
      o[0] = f2b((x.x-mu)*inv*w.x + b.x);
      o[1] = f2b((x.y-mu)*inv*w.y + b.y);
      o[2] = f2b((x.z-mu)*inv*w.z + b.z);
      o[3] = f2b((x.w-mu)*inv*w.w + b.w);
      *(ushort4*)(mnb  + ((size_t)l*256 + s)*256 + ln*4) = *(ushort4*)o;
      *(ushort4*)(mnb2 + ((size_t)s*256 + l)*256 + ln*4) = *(ushort4*)o;
    }
  } else {
    // Weight transpose: 80 blocks; z = 0..4 (wq,wk,wv,wg,wo), 16 n-cols each.
    int bb = bx - 2048;
    int z = bb>>4, n0 = (bb&15)*16;
    const float* W = (z==0)?wq:(z==1)?wk:(z==2)?wv:(z==3)?wg:wo;
    int nl = tid&15;
    #pragma unroll
    for (int i=0;i<16;++i){
      int cm = i*16 + (tid>>4);
      T[nl*264 + cm] = f2b(W[(size_t)cm*256 + n0 + nl]);   // 64B-coalesced reads
    }
    __syncthreads();
    int n = tid>>4, cc = (tid&15)*16;
    uint4 a = *(const uint4*)&T[n*264 + cc];
    uint4 c = *(const uint4*)&T[n*264 + cc + 8];
    *(uint4*)&WT[(size_t)z*65536 + (size_t)(n0+n)*256 + cc]     = a;
    *(uint4*)&WT[(size_t)z*65536 + (size_t)(n0+n)*256 + cc + 8] = c;
  }
}

// ---- K2: fully fused per (l,h): QKV proj -> attention -> gate -> out proj ----
// Out identity: block (l,h) -> out rows (s'=32h+(l>>3), l'=(l&7)*32+j), and
// O_flat[j][n] == o[s][c] at the same flat index (s*32+c == j*256+n).
// Structure = round-2 verified kernel (no spills, 3 blocks/CU); changes:
// hardware f2b + gate reads from mnb2 (contiguous, L2-friendly).
__global__ __launch_bounds__(256,3) void k_fused(const u16* __restrict__ mnb,
    const u16* __restrict__ mnb2, const u16* __restrict__ WT,
    const float* __restrict__ bg, const float* __restrict__ bo,
    float* __restrict__ outp){
  // LDS map (u16 units), total 26880 u16 = 53760 B -> 3 blocks/CU.
  //  QS [256][40] q[s][c]          :     0 .. 10239
  //  KS [256][32] k[t][c]          : 10240 .. 18431
  //  VT [32][264] v^T[c][t]        : 18432 .. 26879
  //  PB per-wave P [64][40]        : aliases QS (QS dead after qf reg-load)
  //  OS f32 [256][32] o            : aliases QS+KS region, after sync
  //  GS [32][264] gated bf16       : aliases VT region, after sync
  __shared__ u16 smem[26880];
  u16* QS = smem;
  u16* KS = smem + 10240;
  u16* VT = smem + 18432;
  u16* PB = smem;            // + wid*64*40 == QS per-wave region
  float* OS = (float*)smem;
  u16* GS = smem + 18432;

  int bx = blockIdx.x;
  // XCD-aware swizzle: XCD = bx%8; each XCD owns a contiguous 32-wide l-range,
  // 8 h-blocks per l adjacent in dispatch order.
  int l = ((bx&7)<<5) | (bx>>6);
  int h = (bx>>3)&7;
  int tid = threadIdx.x;
  int lane = tid&63, wid = tid>>6, quad = lane>>4, lo = lane&15;
  int m0 = wid*64;
  f32x4 z4 = {0.f,0.f,0.f,0.f};

  // ================= Phase 1: QKV projection (head h slice) =================
  const u16* Abase = mnb + (size_t)l*65536;          // mn_l [s][cm]
  const u16* Bq = WT + (size_t)h*32*256;
  const u16* Bk = WT + (size_t)65536 + (size_t)h*32*256;
  const u16* Bv = WT + (size_t)2*65536 + (size_t)h*32*256;
  f32x4 acc[4][6];                                   // nt: 0-1 q, 2-3 k, 4-5 v
  #pragma unroll
  for (int a=0;a<4;++a)
    #pragma unroll
    for (int b=0;b<6;++b) acc[a][b]=z4;

  for (int ks=0; ks<8; ++ks){
    bf16x8 af[4];
    #pragma unroll
    for (int mt=0; mt<4; ++mt)
      af[mt] = *(const bf16x8*)(Abase + (size_t)(m0+mt*16+lo)*256 + ks*32 + quad*8);
    bf16x8 bq[2], bk2[2], bv2[2];
    #pragma unroll
    for (int c2=0; c2<2; ++c2){
      bq[c2]  = *(const bf16x8*)(Bq + (size_t)(c2*16+lo)*256 + ks*32 + quad*8);
      bk2[c2] = *(const bf16x8*)(Bk + (size_t)(c2*16+lo)*256 + ks*32 + quad*8);
      bv2[c2] = *(const bf16x8*)(Bv + (size_t)(c2*16+lo)*256 + ks*32 + quad*8);
    }
    #pragma unroll
    for (int mt=0; mt<4; ++mt){
      #pragma unroll
      for (int c2=0; c2<2; ++c2){
        acc[mt][0+c2] = __builtin_amdgcn_mfma_f32_16x16x32_bf16(af[mt], bq[c2],  acc[mt][0+c2], 0,0,0);
        acc[mt][2+c2] = __builtin_amdgcn_mfma_f32_16x16x32_bf16(af[mt], bk2[c2], acc[mt][2+c2], 0,0,0);
        acc[mt][4+c2] = __builtin_amdgcn_mfma_f32_16x16x32_bf16(af[mt], bv2[c2], acc[mt][4+c2], 0,0,0);
      }
    }
  }
  // scatter q,k (row-major) and v (transposed) to LDS
  #pragma unroll
  for (int mt=0; mt<4; ++mt)
    #pragma unroll
    for (int ntl=0; ntl<2; ++ntl)
      #pragma unroll
      for (int r=0; r<4; ++r){
        int s = m0 + mt*16 + quad*4 + r;
        QS[s*40 + ntl*16+lo] = f2b(acc[mt][0+ntl][r]);
        KS[s*32 + ntl*16+lo] = f2b(acc[mt][2+ntl][r]);
        VT[(ntl*16+lo)*264 + s] = f2b(acc[mt][4+ntl][r]);
      }
  // q-frags are own-wave rows: load before the barrier (QS dead afterwards,
  // so PB can alias it)
  bf16x8 qf[4];
  #pragma unroll
  for (int mt=0; mt<4; ++mt)
    qf[mt] = *(const bf16x8*)&QS[(m0+mt*16+lo)*40 + quad*8];
  __syncthreads();   // B0: KS/VT visible to all waves

  // ================= Phase 2: attention =====================================
  const float scale = 0.17677669529663687f;  // 1/sqrt(32)
  float lr[16];
  #pragma unroll
  for (int i=0;i<16;++i) lr[i]=0.f;
  f32x4 o_acc[4][2];
  #pragma unroll
  for (int a=0;a<4;++a){ o_acc[a][0]=z4; o_acc[a][1]=z4; }
  int pbase = wid*64*40;

  for (int ts=0; ts<8; ++ts){
    bf16x8 kf[2];
    #pragma unroll
    for (int ntl=0; ntl<2; ++ntl)
      kf[ntl] = *(const bf16x8*)&KS[(ts*32+ntl*16+lo)*32 + quad*8];
    bf16x8 vf[2];
    #pragma unroll
    for (int nc=0; nc<2; ++nc)
      vf[nc] = *(const bf16x8*)&VT[(nc*16+lo)*264 + ts*32 + quad*8];
    #pragma unroll
    for (int mt=0; mt<4; ++mt){
      f32x4 sa[2];
      sa[0] = __builtin_amdgcn_mfma_f32_16x16x32_bf16(qf[mt], kf[0], z4, 0,0,0);
      sa[1] = __builtin_amdgcn_mfma_f32_16x16x32_bf16(qf[mt], kf[1], z4, 0,0,0);
      #pragma unroll
      for (int ntl=0; ntl<2; ++ntl)
        #pragma unroll
        for (int r=0; r<4; ++r){
          float p = __expf(sa[ntl][r]*scale);
          lr[mt*4+r] += p;
          PB[pbase + (mt*16+quad*4+r)*40 + ntl*16+lo] = f2b(p);
        }
      bf16x8 paf = *(const bf16x8*)&PB[pbase + (mt*16+lo)*40 + quad*8];
      o_acc[mt][0] = __builtin_amdgcn_mfma_f32_16x16x32_bf16(paf, vf[0], o_acc[mt][0], 0,0,0);
      o_acc[mt][1] = __builtin_amdgcn_mfma_f32_16x16x32_bf16(paf, vf[1], o_acc[mt][1], 0,0,0);
    }
  }
  #pragma unroll
  for (int i=0;i<16;++i){
    float v = lr[i];
    v += __shfl_xor(v, 1);
    v += __shfl_xor(v, 2);
    v += __shfl_xor(v, 4);
    v += __shfl_xor(v, 8);
    lr[i] = 1.0f / v;
  }
  __syncthreads();   // B1: all waves done reading KS/VT/PB before OS overwrites
  // o stays f32 in LDS (no extra rounding vs previous pipeline)
  #pragma unroll
  for (int mt=0; mt<4; ++mt)
    #pragma unroll
    for (int nc=0; nc<2; ++nc)
      #pragma unroll
      for (int r=0; r<4; ++r){
        int s = m0 + mt*16 + quad*4 + r;
        int c = nc*16 + lo;
        OS[s*32 + c] = o_acc[mt][nc][r] * lr[mt*4+r];
      }
  __syncthreads();   // B2: OS visible

  // ================= Phase 3: gate GEMM [32 x 256] ==========================
  int sp  = h*32 + (l>>3);      // s' (constant per block)
  int l0p = (l&7)*32;           // l' base; rows j = 0..31
  int wn0 = wid*64;             // this wave's 64-col slice of n
  const u16* Gw = WT + (size_t)3*65536;   // wg^T [n][cm]
  const u16* A2 = mnb2 + (size_t)sp*65536;  // mn[s=sp][l][cm] (contiguous!)
  f32x4 gacc[2][4];
  #pragma unroll
  for (int a=0;a<2;++a)
    #pragma unroll
    for (int b=0;b<4;++b) gacc[a][b]=z4;
  for (int ks=0; ks<8; ++ks){
    bf16x8 ga[2];
    #pragma unroll
    for (int mt2=0; mt2<2; ++mt2)
      ga[mt2] = *(const bf16x8*)(A2 + (size_t)(l0p+mt2*16+lo)*256 + ks*32 + quad*8);
    bf16x8 gb[4];
    #pragma unroll
    for (int nt=0; nt<4; ++nt)
      gb[nt] = *(const bf16x8*)(Gw + (size_t)(wn0+nt*16+lo)*256 + ks*32 + quad*8);
    #pragma unroll
    for (int mt2=0; mt2<2; ++mt2)
      #pragma unroll
      for (int nt=0; nt<4; ++nt)
        gacc[mt2][nt] = __builtin_amdgcn_mfma_f32_16x16x32_bf16(ga[mt2], gb[nt], gacc[mt2][nt], 0,0,0);
  }
  // sigmoid, multiply by O_flat (pure reinterpret of OS), store bf16 to GS
  #pragma unroll
  for (int nt=0; nt<4; ++nt){
    int n = wn0 + nt*16 + lo;
    float bgn = bg[n];
    #pragma unroll
    for (int mt2=0; mt2<2; ++mt2)
      #pragma unroll
      for (int r=0; r<4; ++r){
        int j = mt2*16 + quad*4 + r;
        float g = 1.f/(1.f + __expf(-(gacc[mt2][nt][r] + bgn)));
        GS[j*264 + n] = f2b(g * OS[j*256 + n]);
      }
  }
  __syncthreads();   // B3: GS visible

  // ================= Phase 4: out projection [32 x 256] =====================
  const u16* Ow = WT + (size_t)4*65536;   // wo^T
  f32x4 pacc[2][4];
  #pragma unroll
  for (int a=0;a<2;++a)
    #pragma unroll
    for (int b=0;b<4;++b) pacc[a][b]=z4;
  for (int ks=0; ks<8; ++ks){
    bf16x8 pa[2];
    #pragma unroll
    for (int mt2=0; mt2<2; ++mt2)
      pa[mt2] = *(const bf16x8*)&GS[(mt2*16+lo)*264 + ks*32 + quad*8];
    bf16x8 pb[4];
    #pragma unroll
    for (int nt=0; nt<4; ++nt)
      pb[nt] = *(const bf16x8*)(Ow + (size_t)(wn0+nt*16+lo)*256 + ks*32 + quad*8);
    #pragma unroll
    for (int mt2=0; mt2<2; ++mt2)
      #pragma unroll
      for (int nt=0; nt<4; ++nt)
        pacc[mt2][nt] = __builtin_amdgcn_mfma_f32_16x16x32_bf16(pa[mt2], pb[nt], pacc[mt2][nt], 0,0,0);
  }
  #pragma unroll
  for (int nt=0; nt<4; ++nt){
    int n = wn0 + nt*16 + lo;
    float bon = bo[n];
    #pragma unroll
    for (int mt2=0; mt2<2; ++mt2)
      #pragma unroll
      for (int r=0; r<4; ++r){
        int j = mt2*16 + quad*4 + r;
        outp[((size_t)sp*256 + l0p + j)*256 + n] = pacc[mt2][nt][r] + bon;
      }
  }
}

extern "C" void kernel_launch(void* const* d_in, const int* in_sizes, int n_in,
                              void* d_out, int out_size, void* d_ws, size_t ws_size,
                              hipStream_t stream){
  const float* m  = (const float*)d_in[0];
  const float* lw = (const float*)d_in[1];
  const float* lb = (const float*)d_in[2];
  const float* wq = (const float*)d_in[3];
  const float* wk = (const float*)d_in[4];
  const float* wv = (const float*)d_in[5];
  const float* wg = (const float*)d_in[6];
  const float* bg = (const float*)d_in[7];
  const float* wo = (const float*)d_in[8];
  const float* bo = (const float*)d_in[9];

  // ws: mnb bf16 [l][s][cm] 32MiB | mnb2 bf16 [s][l][cm] 32MiB | WT 640KiB
  u16* mnb  = (u16*)d_ws;
  u16* mnb2 = mnb  + (size_t)16777216;
  u16* WT   = mnb2 + (size_t)16777216;
  float* out = (float*)d_out;

  k_pre  <<<2128, 256, 0, stream>>>(m, lw, lb, wq, wk, wv, wg, wo, mnb, mnb2, WT);
  k_fused<<<2048, 256, 0, stream>>>(mnb, mnb2, WT, bg, bo, out);
}

// Round 5
// 300.404 us; speedup vs baseline: 1.1833x; 1.0271x over previous
//
#include <hip/hip_runtime.h>

typedef unsigned short u16;
typedef __attribute__((ext_vector_type(8))) short bf16x8;   // 8 bf16 = 4 VGPR
typedef __attribute__((ext_vector_type(4))) float f32x4;

// Hardware round-to-nearest-even f32->bf16 (single v_cvt instr on gfx950).
__device__ __forceinline__ u16 f2b(float f){
  __bf16 h = (__bf16)f;
  return __builtin_bit_cast(u16, h);
}

// async global->LDS, 16B per lane: LDS gets base + lane*16 (wave-uniform base).
__device__ __forceinline__ void gload_lds16(const void* g, void* l){
  __builtin_amdgcn_global_load_lds(
      (const __attribute__((address_space(1))) unsigned int*)g,
      (__attribute__((address_space(3))) unsigned int*)l, 16, 0, 0);
}

// ---- K1: prep. bx<2048: LayerNorm -> bf16 mnb [l][s][cm].
//          bx>=2048: weight transpose to bf16 WT[z][n][cm]. ----
__global__ __launch_bounds__(256) void k_pre(const float* __restrict__ m,
    const float* __restrict__ lw, const float* __restrict__ lb,
    const float* __restrict__ wq, const float* __restrict__ wk,
    const float* __restrict__ wv, const float* __restrict__ wg,
    const float* __restrict__ wo,
    u16* __restrict__ mnb, u16* __restrict__ WT){
  __shared__ u16 T[16*264];
  int bx = blockIdx.x, tid = threadIdx.x;
  if (bx < 2048){
    // LN: block = (l, 32-row s-band). 2 rows per wave per iter (half-wave
    // reduction: 5 shuffle levels, not 6).
    int l = bx>>3;
    int w = tid>>6, ln = tid&63, half = ln>>5, lh = ln&31;
    float4 wa = *(const float4*)(lw + lh*8);
    float4 wb = *(const float4*)(lw + lh*8 + 4);
    float4 ba = *(const float4*)(lb + lh*8);
    float4 bb = *(const float4*)(lb + lh*8 + 4);
    #pragma unroll
    for (int i=0;i<4;++i){
      int s = (bx&7)*32 + w*8 + i*2 + half;
      const float* mp = m + ((size_t)s*256 + l)*256 + lh*8;
      float4 xa = *(const float4*)mp;
      float4 xb = *(const float4*)(mp+4);
      float s1 = (xa.x+xa.y)+(xa.z+xa.w) + (xb.x+xb.y)+(xb.z+xb.w);
      float s2 = xa.x*xa.x+xa.y*xa.y+xa.z*xa.z+xa.w*xa.w
               + xb.x*xb.x+xb.y*xb.y+xb.z*xb.z+xb.w*xb.w;
      #pragma unroll
      for (int off=16; off>0; off>>=1){
        s1 += __shfl_xor(s1, off);
        s2 += __shfl_xor(s2, off);
      }
      float mu  = s1*(1.0f/256.0f);
      float inv = rsqrtf(s2*(1.0f/256.0f) - mu*mu + 1e-5f);
      u16 o[8];
      o[0]=f2b((xa.x-mu)*inv*wa.x+ba.x);
      o[1]=f2b((xa.y-mu)*inv*wa.y+ba.y);
      o[2]=f2b((xa.z-mu)*inv*wa.z+ba.z);
      o[3]=f2b((xa.w-mu)*inv*wa.w+ba.w);
      o[4]=f2b((xb.x-mu)*inv*wb.x+bb.x);
      o[5]=f2b((xb.y-mu)*inv*wb.y+bb.y);
      o[6]=f2b((xb.z-mu)*inv*wb.z+bb.z);
      o[7]=f2b((xb.w-mu)*inv*wb.w+bb.w);
      u16* op = mnb + ((size_t)l*256 + s)*256 + lh*8;
      *(ushort4*)op     = *(ushort4*)&o[0];
      *(ushort4*)(op+4) = *(ushort4*)&o[4];
    }
  } else {
    // Weight transpose: 80 blocks; z = 0..4 (wq,wk,wv,wg,wo), 16 n-cols each.
    int bb = bx - 2048;
    int z = bb>>4, n0 = (bb&15)*16;
    const float* W = (z==0)?wq:(z==1)?wk:(z==2)?wv:(z==3)?wg:wo;
    int nl = tid&15;
    #pragma unroll
    for (int i=0;i<16;++i){
      int cm = i*16 + (tid>>4);
      T[nl*264 + cm] = f2b(W[(size_t)cm*256 + n0 + nl]);
    }
    __syncthreads();
    int n = tid>>4, cc = (tid&15)*16;
    uint4 a = *(const uint4*)&T[n*264 + cc];
    uint4 c = *(const uint4*)&T[n*264 + cc + 8];
    *(uint4*)&WT[(size_t)z*65536 + (size_t)(n0+n)*256 + cc]     = a;
    *(uint4*)&WT[(size_t)z*65536 + (size_t)(n0+n)*256 + cc + 8] = c;
  }
}

// ---- K2: fully fused per (l,h): QKV proj -> attention -> gate -> out proj ----
// Out identity: block (l,h) -> out rows (s'=32h+(l>>3), l'=(l&7)*32+j), and
// O_flat[j][n] == o[s][c] at the same flat index (s*32+c == j*256+n).
__global__ __launch_bounds__(256,3) void k_fused(const u16* __restrict__ mnb,
    const u16* __restrict__ WT, const float* __restrict__ bg,
    const float* __restrict__ bo, float* __restrict__ outp){
  // LDS u16 map, total 27136 u16 = 54272 B -> 3 blocks/CU.
  //  SC  [4 waves][16][40]   :     0 ..  2559  (per-wave q- and P-transpose)
  //  KS  [256][32] k[t][c]   :  2560 .. 10751
  //  VT2 [32 tb][32 c][8] v^T: 10752 .. 18943  (subtiled: contiguous frags)
  //  GA  [32][256] gate-A    : 18944 .. 27135  (async prefetch, src-swizzled)
  //  OS  f32 [256][32]       : u16 0..16383   (after B1; SC/KS/VT2 dead)
  //  GS  [32][264] gated bf16: u16 16384..24831 (after B3a; GA dead)
  __shared__ u16 smem[27136];
  u16* KS  = smem + 2560;
  u16* VT2 = smem + 10752;
  u16* GAB = smem + 18944;
  float* OS = (float*)smem;
  u16* GS  = smem + 16384;

  int bx = blockIdx.x;
  // XCD-aware swizzle: XCD = bx%8; each XCD owns a contiguous 32-wide l-range,
  // 8 h-blocks per l adjacent in dispatch order.
  int l = ((bx&7)<<5) | (bx>>6);
  int h = (bx>>3)&7;
  int tid = threadIdx.x;
  int lane = tid&63, wid = tid>>6, quad = lane>>4, lo = lane&15;
  int m0 = wid*64;
  u16* SC = smem + wid*640;
  f32x4 z4 = {0.f,0.f,0.f,0.f};
  int sp  = h*32 + (l>>3);      // s' (constant per block)
  int l0p = (l&7)*32;           // l' base; rows j = 0..31

  // ---- async prefetch of gate-A tile mn[sp][l0p+0..31][:] (16 KB bf16) ----
  // LDS dest linear (HW: base + lane*16); global SOURCE pre-swizzled with
  // byte ^= ((row&7)<<4) so the swizzled phase-3 read is bank-spread.
  // Latency hides under phases 1-2 (every barrier drains vmcnt).
  {
    const char* mb = (const char*)mnb;
    #pragma unroll
    for (int c2=0;c2<4;++c2){
      int r   = wid*8 + c2*2 + (lane>>5);
      int dst = (wid*8 + c2*2)*256;
      size_t src = (size_t)(l0p + r)*131072 + (size_t)sp*512
                 + (size_t)((((lane&31)*16) ^ ((r&7)<<4)));
      gload_lds16(mb + src, &GAB[dst]);
    }
  }

  // ================= Phase 1: QKV projection (head h slice) =================
  const u16* Abase = mnb + (size_t)l*65536;          // mn_l [s][cm]
  const u16* Bq = WT + (size_t)h*32*256;
  const u16* Bk = WT + (size_t)65536 + (size_t)h*32*256;
  const u16* Bv = WT + (size_t)2*65536 + (size_t)h*32*256;
  f32x4 acc[4][6];                                   // nt: 0-1 q, 2-3 k, 4-5 v
  #pragma unroll
  for (int a=0;a<4;++a)
    #pragma unroll
    for (int b=0;b<6;++b) acc[a][b]=z4;

  for (int ks=0; ks<8; ++ks){
    bf16x8 af[4];
    #pragma unroll
    for (int mt=0; mt<4; ++mt)
      af[mt] = *(const bf16x8*)(Abase + (size_t)(m0+mt*16+lo)*256 + ks*32 + quad*8);
    bf16x8 bq[2], bk2[2], bv2[2];
    #pragma unroll
    for (int c2=0; c2<2; ++c2){
      bq[c2]  = *(const bf16x8*)(Bq + (size_t)(c2*16+lo)*256 + ks*32 + quad*8);
      bk2[c2] = *(const bf16x8*)(Bk + (size_t)(c2*16+lo)*256 + ks*32 + quad*8);
      bv2[c2] = *(const bf16x8*)(Bv + (size_t)(c2*16+lo)*256 + ks*32 + quad*8);
    }
    #pragma unroll
    for (int mt=0; mt<4; ++mt){
      #pragma unroll
      for (int c2=0; c2<2; ++c2){
        acc[mt][0+c2] = __builtin_amdgcn_mfma_f32_16x16x32_bf16(af[mt], bq[c2],  acc[mt][0+c2], 0,0,0);
        acc[mt][2+c2] = __builtin_amdgcn_mfma_f32_16x16x32_bf16(af[mt], bk2[c2], acc[mt][2+c2], 0,0,0);
        acc[mt][4+c2] = __builtin_amdgcn_mfma_f32_16x16x32_bf16(af[mt], bv2[c2], acc[mt][4+c2], 0,0,0);
      }
    }
  }
  // scatter k (row-major) and v (subtiled-transposed) to LDS
  #pragma unroll
  for (int mt=0; mt<4; ++mt)
    #pragma unroll
    for (int ntl=0; ntl<2; ++ntl)
      #pragma unroll
      for (int r=0; r<4; ++r){
        int t = m0 + mt*16 + quad*4 + r;
        int c = ntl*16 + lo;
        KS[t*32 + c] = f2b(acc[mt][2+ntl][r]);
        VT2[(t>>3)*256 + c*8 + (t&7)] = f2b(acc[mt][4+ntl][r]);
      }
  // q transpose via per-wave scratch (wave-private; R3-proven pattern)
  bf16x8 qf[4];
  #pragma unroll
  for (int mt=0; mt<4; ++mt){
    #pragma unroll
    for (int ntl=0; ntl<2; ++ntl)
      #pragma unroll
      for (int r=0; r<4; ++r)
        SC[(quad*4+r)*40 + ntl*16+lo] = f2b(acc[mt][0+ntl][r]);
    qf[mt] = *(const bf16x8*)&SC[lo*40 + quad*8];
  }
  __syncthreads();   // B0: KS/VT2 visible (also drains GA vmcnt)

  // ================= Phase 2: attention =====================================
  const float scale = 0.17677669529663687f;  // 1/sqrt(32)
  float lr[16];
  #pragma unroll
  for (int i=0;i<16;++i) lr[i]=0.f;
  f32x4 o_acc[4][2];
  #pragma unroll
  for (int a=0;a<4;++a){ o_acc[a][0]=z4; o_acc[a][1]=z4; }

  for (int ts=0; ts<8; ++ts){
    bf16x8 kf[2];
    #pragma unroll
    for (int ntl=0; ntl<2; ++ntl)
      kf[ntl] = *(const bf16x8*)&KS[(ts*32+ntl*16+lo)*32 + quad*8];
    bf16x8 vf[2];
    #pragma unroll
    for (int nc=0; nc<2; ++nc)
      vf[nc] = *(const bf16x8*)&VT2[(ts*4+quad)*256 + (nc*16+lo)*8];
    #pragma unroll
    for (int mt=0; mt<4; ++mt){
      f32x4 sa[2];
      sa[0] = __builtin_amdgcn_mfma_f32_16x16x32_bf16(qf[mt], kf[0], z4, 0,0,0);
      sa[1] = __builtin_amdgcn_mfma_f32_16x16x32_bf16(qf[mt], kf[1], z4, 0,0,0);
      #pragma unroll
      for (int ntl=0; ntl<2; ++ntl)
        #pragma unroll
        for (int r=0; r<4; ++r){
          float p = __expf(sa[ntl][r]*scale);
          lr[mt*4+r] += p;
          SC[(quad*4+r)*40 + ntl*16+lo] = f2b(p);
        }
      bf16x8 paf = *(const bf16x8*)&SC[lo*40 + quad*8];
      o_acc[mt][0] = __builtin_amdgcn_mfma_f32_16x16x32_bf16(paf, vf[0], o_acc[mt][0], 0,0,0);
      o_acc[mt][1] = __builtin_amdgcn_mfma_f32_16x16x32_bf16(paf, vf[1], o_acc[mt][1], 0,0,0);
    }
  }
  #pragma unroll
  for (int i=0;i<16;++i){
    float v = lr[i];
    v += __shfl_xor(v, 1);
    v += __shfl_xor(v, 2);
    v += __shfl_xor(v, 4);
    v += __shfl_xor(v, 8);
    lr[i] = 1.0f / v;
  }
  __syncthreads();   // B1: all waves done reading KS/VT2/SC
  // o stays f32 in LDS (no extra rounding vs verified pipeline)
  #pragma unroll
  for (int mt=0; mt<4; ++mt)
    #pragma unroll
    for (int nc=0; nc<2; ++nc)
      #pragma unroll
      for (int r=0; r<4; ++r){
        int s = m0 + mt*16 + quad*4 + r;
        int c = nc*16 + lo;
        OS[s*32 + c] = o_acc[mt][nc][r] * lr[mt*4+r];
      }
  __syncthreads();   // B2: OS (and GA, long since landed) visible

  // ================= Phase 3: gate GEMM [32 x 256] ==========================
  int wn0 = wid*64;             // this wave's 64-col slice of n
  const u16* Gw = WT + (size_t)3*65536;   // wg^T [n][cm]
  f32x4 gacc[2][4];
  #pragma unroll
  for (int a=0;a<2;++a)
    #pragma unroll
    for (int b=0;b<4;++b) gacc[a][b]=z4;
  for (int ks=0; ks<8; ++ks){
    bf16x8 ga[2];
    #pragma unroll
    for (int mt2=0; mt2<2; ++mt2){
      int j = mt2*16 + lo;
      ga[mt2] = *(const bf16x8*)&GAB[j*256 + ((ks*32 + quad*8) ^ ((j&7)<<3))];
    }
    bf16x8 gb[4];
    #pragma unroll
    for (int nt=0; nt<4; ++nt)
      gb[nt] = *(const bf16x8*)(Gw + (size_t)(wn0+nt*16+lo)*256 + ks*32 + quad*8);
    #pragma unroll
    for (int mt2=0; mt2<2; ++mt2)
      #pragma unroll
      for (int nt=0; nt<4; ++nt)
        gacc[mt2][nt] = __builtin_amdgcn_mfma_f32_16x16x32_bf16(ga[mt2], gb[nt], gacc[mt2][nt], 0,0,0);
  }
  __syncthreads();   // B3a: GA reads done; its region may now hold GS
  // sigmoid, multiply by O_flat (pure reinterpret of OS), store bf16 to GS
  #pragma unroll
  for (int nt=0; nt<4; ++nt){
    int n = wn0 + nt*16 + lo;
    float bgn = bg[n];
    #pragma unroll
    for (int mt2=0; mt2<2; ++mt2)
      #pragma unroll
      for (int r=0; r<4; ++r){
        int j = mt2*16 + quad*4 + r;
        float g = 1.f/(1.f + __expf(-(gacc[mt2][nt][r] + bgn)));
        GS[j*264 + n] = f2b(g * OS[j*256 + n]);
      }
  }
  __syncthreads();   // B3b: GS visible

  // ================= Phase 4: out projection [32 x 256] =====================
  const u16* Ow = WT + (size_t)4*65536;   // wo^T
  f32x4 pacc[2][4];
  #pragma unroll
  for (int a=0;a<2;++a)
    #pragma unroll
    for (int b=0;b<4;++b) pacc[a][b]=z4;
  for (int ks=0; ks<8; ++ks){
    bf16x8 pa[2];
    #pragma unroll
    for (int mt2=0; mt2<2; ++mt2)
      pa[mt2] = *(const bf16x8*)&GS[(mt2*16+lo)*264 + ks*32 + quad*8];
    bf16x8 pb[4];
    #pragma unroll
    for (int nt=0; nt<4; ++nt)
      pb[nt] = *(const bf16x8*)(Ow + (size_t)(wn0+nt*16+lo)*256 + ks*32 + quad*8);
    #pragma unroll
    for (int mt2=0; mt2<2; ++mt2)
      #pragma unroll
      for (int nt=0; nt<4; ++nt)
        pacc[mt2][nt] = __builtin_amdgcn_mfma_f32_16x16x32_bf16(pa[mt2], pb[nt], pacc[mt2][nt], 0,0,0);
  }
  #pragma unroll
  for (int nt=0; nt<4; ++nt){
    int n = wn0 + nt*16 + lo;
    float bon = bo[n];
    #pragma unroll
    for (int mt2=0; mt2<2; ++mt2)
      #pragma unroll
      for (int r=0; r<4; ++r){
        int j = mt2*16 + quad*4 + r;
        outp[((size_t)sp*256 + l0p + j)*256 + n] = pacc[mt2][nt][r] + bon;
      }
  }
}

extern "C" void kernel_launch(void* const* d_in, const int* in_sizes, int n_in,
                              void* d_out, int out_size, void* d_ws, size_t ws_size,
                              hipStream_t stream){
  const float* m  = (const float*)d_in[0];
  const float* lw = (const float*)d_in[1];
  const float* lb = (const float*)d_in[2];
  const float* wq = (const float*)d_in[3];
  const float* wk = (const float*)d_in[4];
  const float* wv = (const float*)d_in[5];
  const float* wg = (const float*)d_in[6];
  const float* bg = (const float*)d_in[7];
  const float* wo = (const float*)d_in[8];
  const float* bo = (const float*)d_in[9];

  // ws: mnb bf16 [l][s][cm] = 32 MiB | WT bf16 [5][256][256] = 640 KiB
  u16* mnb = (u16*)d_ws;
  u16* WT  = mnb + (size_t)16777216;
  float* out = (float*)d_out;

  k_pre  <<<2128, 256, 0, stream>>>(m, lw, lb, wq, wk, wv, wg, wo, mnb, WT);
  k_fused<<<2048, 256, 0, stream>>>(mnb, WT, bg, bo, out);
}